// Round 17
// baseline (2336.783 us; speedup 1.0000x reference)
//
#include <hip/hip_runtime.h>

typedef unsigned int u32;
typedef unsigned short u16;

typedef __attribute__((ext_vector_type(8))) __bf16 bf16x8;
typedef __attribute__((ext_vector_type(4))) float f32x4;

__device__ __forceinline__ u16 f2bf(float f) {
  u32 u = __float_as_uint(f);
  u += 0x7fffu + ((u >> 16) & 1u);
  return (u16)(u >> 16);
}
__device__ __forceinline__ float bl(u32 u) { return __uint_as_float(u << 16); }
__device__ __forceinline__ float bh(u32 u) { return __uint_as_float(u & 0xffff0000u); }
__device__ __forceinline__ u32 pk2(float a, float b) { return (u32)f2bf(a) | ((u32)f2bf(b) << 16); }
__device__ __forceinline__ float fsig(float x) { return 1.f / (1.f + __expf(-x)); }
__device__ __forceinline__ float ftanh(float x) { return 1.f - 2.f / (__expf(2.f * x) + 1.f); }

#define GLDS16(gp, lp)                                                                  \
  __builtin_amdgcn_global_load_lds((const __attribute__((address_space(1))) u32*)(gp),  \
                                   (__attribute__((address_space(3))) u32*)(lp), 16, 0, 0)

// ---------- batched weight transpose+cast: wt[c*K+k] = bf16(w[k*N+c]) ----------
struct WTargs {
  const float* src[13];
  u16* dst[13];
  int K[13];
  int Nc[13];
  int bstart[14];
};
__global__ __launch_bounds__(256) void k_wtall(WTargs wa) {
  int b = blockIdx.x;
  int w = 0;
  while (b >= wa.bstart[w + 1]) ++w;
  int i = (b - wa.bstart[w]) * 256 + threadIdx.x;
  int K = wa.K[w], Nc = wa.Nc[w];
  if (i >= K * Nc) return;
  int k = i / Nc, c = i - k * Nc;
  wa.dst[w][(size_t)c * K + k] = f2bf(wa.src[w][i]);
}

// ---------- x fp32 [N,512] -> bf16 xb ----------
__global__ __launch_bounds__(256) void k_x2bf(const float* __restrict__ x, u16* __restrict__ xb, int total8) {
  int i = blockIdx.x * 256 + threadIdx.x;
  if (i >= total8) return;
  size_t o = (size_t)i * 8;
  float4 a = *(const float4*)(x + o), b = *(const float4*)(x + o + 4);
  uint4 v;
  v.x = pk2(a.x, a.y); v.y = pk2(a.z, a.w); v.z = pk2(b.x, b.y); v.w = pk2(b.z, b.w);
  *(uint4*)(xb + o) = v;
}

// ---------- CSR build ----------
__global__ void k_hist(const int* __restrict__ dst, int* __restrict__ deg, int E) {
  int e = blockIdx.x * 256 + threadIdx.x;
  if (e < E) atomicAdd(&deg[dst[e]], 1);
}
__global__ __launch_bounds__(1024) void k_scan1(const int* __restrict__ deg, int* __restrict__ rs,
                                                int* __restrict__ bsum, int n) {
  __shared__ int buf[1024];
  int t = threadIdx.x, idx = blockIdx.x * 1024 + t;
  int v = idx < n ? deg[idx] : 0;
  buf[t] = v;
  __syncthreads();
  for (int off = 1; off < 1024; off <<= 1) {
    int u = t >= off ? buf[t - off] : 0;
    __syncthreads();
    buf[t] += u;
    __syncthreads();
  }
  if (idx < n) rs[idx + 1] = buf[t];
  if (t == 1023) bsum[blockIdx.x] = buf[1023];
}
__global__ void k_scan2(int* bsum, int nb) {
  if (threadIdx.x == 0) {
    int s = 0;
    for (int b = 0; b < nb; ++b) { s += bsum[b]; bsum[b] = s; }
  }
}
__global__ void k_scan3(const int* __restrict__ bsum, int* __restrict__ rs,
                        int* __restrict__ cursor, int n) {
  int i = blockIdx.x * 256 + threadIdx.x;
  if (i >= n) return;
  int b = i >> 10;
  int add = b ? bsum[b - 1] : 0;
  int v = rs[i + 1] + add;  // inclusive prefix
  int d = cursor[i];        // deg
  rs[i + 1] = v;
  cursor[i] = v - d;        // exclusive prefix = scatter cursor
  if (i == 0) rs[0] = 0;
}
__global__ void k_scatter(const int* __restrict__ src, const int* __restrict__ dst,
                          int* __restrict__ cursor, int* __restrict__ esrc, int E) {
  int e = blockIdx.x * 256 + threadIdx.x;
  if (e < E) {
    int p = atomicAdd(&cursor[dst[e]], 1);
    esrc[p] = src[e];
  }
}

// ---------- conv1 projected-space gather: z = relu(y[node] + sum_nb y[src] + b1) ----------
__global__ __launch_bounds__(256) void k_aggbr(const u16* __restrict__ y, const int* __restrict__ rowstart,
                                               const int* __restrict__ esrc, const float* __restrict__ b1,
                                               u16* __restrict__ z, int Nn, int base, int rows) {
  int lane = threadIdx.x & 63, wid = threadIdx.x >> 6;
  int r = blockIdx.x * 4 + wid;
  if (r >= rows) return;
  int node = base + r;
  const int cb = lane * 4;
  u16* orow = z + (size_t)r * 256 + cb;
  if (node >= Nn) { *(uint2*)orow = uint2{0, 0}; return; }
  float acc[4];
  {
    uint2 v = *(const uint2*)(y + (size_t)node * 256 + cb);
    acc[0] = bl(v.x); acc[1] = bh(v.x); acc[2] = bl(v.y); acc[3] = bh(v.y);
  }
  int s = rowstart[node], e = rowstart[node + 1];
  int j = s;
  for (; j + 3 < e; j += 4) {
    uint2 v0 = *(const uint2*)(y + (size_t)esrc[j] * 256 + cb);
    uint2 v1 = *(const uint2*)(y + (size_t)esrc[j + 1] * 256 + cb);
    uint2 v2 = *(const uint2*)(y + (size_t)esrc[j + 2] * 256 + cb);
    uint2 v3 = *(const uint2*)(y + (size_t)esrc[j + 3] * 256 + cb);
    acc[0] += (bl(v0.x) + bl(v1.x)) + (bl(v2.x) + bl(v3.x));
    acc[1] += (bh(v0.x) + bh(v1.x)) + (bh(v2.x) + bh(v3.x));
    acc[2] += (bl(v0.y) + bl(v1.y)) + (bl(v2.y) + bl(v3.y));
    acc[3] += (bh(v0.y) + bh(v1.y)) + (bh(v2.y) + bh(v3.y));
  }
  for (; j < e; ++j) {
    uint2 v = *(const uint2*)(y + (size_t)esrc[j] * 256 + cb);
    acc[0] += bl(v.x); acc[1] += bh(v.x); acc[2] += bl(v.y); acc[3] += bh(v.y);
  }
  float4 bb = *(const float4*)(b1 + cb);
  acc[0] = fmaxf(acc[0] + bb.x, 0.f);
  acc[1] = fmaxf(acc[1] + bb.y, 0.f);
  acc[2] = fmaxf(acc[2] + bb.z, 0.f);
  acc[3] = fmaxf(acc[3] + bb.w, 0.f);
  uint2 o;
  o.x = pk2(acc[0], acc[1]); o.y = pk2(acc[2], acc[3]);
  *(uint2*)orow = o;
}

// ---------- conv2-4 aggregation from bf16 h [Mpad,256] ----------
__global__ __launch_bounds__(256) void k_agg256(const u16* __restrict__ h,
                                                const int* __restrict__ rowstart,
                                                const int* __restrict__ esrc,
                                                u16* __restrict__ out, int Nn, int base, int rows) {
  int lane = threadIdx.x & 63, wid = threadIdx.x >> 6;
  int r = blockIdx.x * 4 + wid;
  if (r >= rows) return;
  int node = base + r;
  const int cb = lane * 4;
  u16* orow = out + (size_t)r * 256 + cb;
  if (node >= Nn) { *(uint2*)orow = uint2{0, 0}; return; }
  float acc[4];
  {
    uint2 v = *(const uint2*)(h + (size_t)node * 256 + cb);
    acc[0] = bl(v.x); acc[1] = bh(v.x); acc[2] = bl(v.y); acc[3] = bh(v.y);
  }
  int s = rowstart[node], e = rowstart[node + 1];
  int j = s;
  for (; j + 3 < e; j += 4) {
    uint2 v0 = *(const uint2*)(h + (size_t)esrc[j] * 256 + cb);
    uint2 v1 = *(const uint2*)(h + (size_t)esrc[j + 1] * 256 + cb);
    uint2 v2 = *(const uint2*)(h + (size_t)esrc[j + 2] * 256 + cb);
    uint2 v3 = *(const uint2*)(h + (size_t)esrc[j + 3] * 256 + cb);
    acc[0] += (bl(v0.x) + bl(v1.x)) + (bl(v2.x) + bl(v3.x));
    acc[1] += (bh(v0.x) + bh(v1.x)) + (bh(v2.x) + bh(v3.x));
    acc[2] += (bl(v0.y) + bl(v1.y)) + (bl(v2.y) + bl(v3.y));
    acc[3] += (bh(v0.y) + bh(v1.y)) + (bh(v2.y) + bh(v3.y));
  }
  for (; j < e; ++j) {
    uint2 v = *(const uint2*)(h + (size_t)esrc[j] * 256 + cb);
    acc[0] += bl(v.x); acc[1] += bh(v.x); acc[2] += bl(v.y); acc[3] += bh(v.y);
  }
  uint2 o;
  o.x = pk2(acc[0], acc[1]); o.y = pk2(acc[2], acc[3]);
  *(uint2*)orow = o;
}

// ---------- bf16 MFMA GEMM: glds staging + XOR-swizzled LDS + bijective XCD swizzle ----------
// tile BM x BN, BK=64, 4 waves (2x2); per-wave (BM/2)x(BN/2) = acc[BM/32][BN/32] frags.
// MODE 0: bf16 out, 1: relu bf16 out, 2: relu fp32 out; MODE 3: fused LSTM gates
// (gate-sliced B tiles, c-state bf16, hsum bf16) with BM=256 to double MFMA per barrier pair.
template <int BM, int BN, int MODE>
__global__ __launch_bounds__(256) void k_gemm(const u16* __restrict__ A1, const u16* __restrict__ B1, int K1,
                                              const u16* __restrict__ A2, const u16* __restrict__ B2, int K2,
                                              const float* __restrict__ bias, float bscale,
                                              void* __restrict__ outp, int Nout, int Mstore, int NT,
                                              u16* __restrict__ cstp, u16* __restrict__ hsump,
                                              int first, int dosum) {
  constexpr int MF = BM / 32;  // m-frags per wave
  constexpr int NF = BN / 32;  // n-frags per wave
  __shared__ u16 Al[BM * 64];
  __shared__ u16 Bl[BN * 64];
  const int tid = threadIdx.x;
  const int lane = tid & 63, wid = tid >> 6;
  const int wr = wid >> 1, wc = wid & 1;
  // bijective XCD swizzle (m204)
  const int nwg = gridDim.x;
  const int orig = blockIdx.x;
  const int q = nwg >> 3, rr8 = nwg & 7;
  const int xcd = orig & 7;
  const int wgid = (xcd < rr8 ? xcd * (q + 1) : rr8 * (q + 1) + (xcd - rr8) * q) + (orig >> 3);
  const int mtile = wgid / NT, ntile = wgid - mtile * NT;
  const int m0 = mtile * BM;
  const int n0 = ntile * BN;       // MODE<3 column base
  const int h0 = ntile * 32;       // MODE==3 hcol base
  const int l15 = lane & 15, l4 = lane >> 4;
  const int srow = lane >> 3;
  const int scol = ((lane & 7) ^ (lane >> 3)) * 8;  // pre-swizzled global column slot
  const int rsw = l15 & 7;                          // read-side row XOR key
  f32x4 acc[MF][NF] = {};

  for (int s = 0; s < 2; ++s) {
    const u16* A = s ? A2 : A1;
    const u16* B = s ? B2 : B1;
    const int K = s ? K2 : K1;
    if (A == nullptr) continue;
    for (int k0 = 0; k0 < K; k0 += 64) {
      __syncthreads();  // previous tile's LDS reads done before overwrite
#pragma unroll
      for (int p = 0; p < MF; ++p) {
        int r = m0 + p * 32 + wid * 8 + srow;
        GLDS16(A + (size_t)r * K + k0 + scol, &Al[(p * 32 + wid * 8) * 64]);
      }
#pragma unroll
      for (int p = 0; p < NF; ++p) {
        int r;
        if constexpr (MODE == 3) r = p * 256 + h0 + wid * 8 + srow;  // gate p rows
        else r = n0 + p * 32 + wid * 8 + srow;
        GLDS16(B + (size_t)r * K + k0 + scol, &Bl[(p * 32 + wid * 8) * 64]);
      }
      __syncthreads();  // compiler drains vmcnt before barrier
#pragma unroll
      for (int ks = 0; ks < 2; ++ks) {
        const int sp = (((ks * 4 + l4) ^ rsw)) * 8;  // swizzled 16B-slot within row
        bf16x8 af[MF], bfr[NF];
#pragma unroll
        for (int m = 0; m < MF; ++m)
          af[m] = *(const bf16x8*)&Al[(wr * (BM / 2) + m * 16 + l15) * 64 + sp];
#pragma unroll
        for (int n = 0; n < NF; ++n) {
          int trow;
          if constexpr (MODE == 3) trow = n * 32 + wc * 16 + l15;  // gate n, hcol subset
          else trow = wc * (BN / 2) + n * 16 + l15;
          bfr[n] = *(const bf16x8*)&Bl[trow * 64 + sp];
        }
#pragma unroll
        for (int m = 0; m < MF; ++m)
#pragma unroll
          for (int n = 0; n < NF; ++n)
            acc[m][n] = __builtin_amdgcn_mfma_f32_16x16x32_bf16(af[m], bfr[n], acc[m][n], 0, 0, 0);
      }
    }
  }

  if constexpr (MODE == 3) {
    const int hcol = h0 + wc * 16 + l15;
    const float bi = bias[hcol], bf2 = bias[256 + hcol];
    const float bg = bias[512 + hcol], bo = bias[768 + hcol];
    u16* hout = (u16*)outp;
#pragma unroll
    for (int m = 0; m < MF; ++m) {
      int gr0 = m0 + wr * (BM / 2) + m * 16 + l4 * 4;
#pragma unroll
      for (int r = 0; r < 4; ++r) {
        int gr = gr0 + r;
        if (gr >= Mstore) continue;
        float gi = acc[m][0][r] + bi;
        float gf = acc[m][1][r] + bf2;
        float gg = acc[m][2][r] + bg;
        float go = acc[m][3][r] + bo;
        size_t o = (size_t)gr * 256 + hcol;
        float nc = fsig(gi) * ftanh(gg);
        if (!first) nc += fsig(gf) * bl((u32)cstp[o]);
        cstp[o] = f2bf(nc);
        nc = bl((u32)f2bf(nc));  // use stored-precision c for h (consistency)
        float h = fsig(go) * ftanh(nc);
        hout[o] = f2bf(h);
        if (dosum) {
          if (first) hsump[o] = f2bf(h);
          else hsump[o] = f2bf(bl((u32)hsump[o]) + h);
        }
      }
    }
    return;
  }

#pragma unroll
  for (int m = 0; m < MF; ++m) {
    int gr0 = m0 + wr * (BM / 2) + m * 16 + l4 * 4;
#pragma unroll
    for (int n = 0; n < NF; ++n) {
      int gc = n0 + wc * (BN / 2) + n * 16 + l15;
      float bb = bias ? bias[gc] * bscale : 0.f;
#pragma unroll
      for (int r = 0; r < 4; ++r) {
        int gr = gr0 + r;
        if (gr >= Mstore) continue;
        float v = acc[m][n][r] + bb;
        if (MODE >= 1) v = fmaxf(v, 0.f);
        if (MODE == 2) ((float*)outp)[(size_t)gr * Nout + gc] = v;
        else ((u16*)outp)[(size_t)gr * Nout + gc] = f2bf(v);
      }
    }
  }
}

// ---------- residual cascade in place ----------
__global__ __launch_bounds__(256) void k_cascade(const u16* __restrict__ x1, u16* __restrict__ x2,
                                                 u16* __restrict__ x3, u16* __restrict__ x4, int total4) {
  int i = blockIdx.x * 256 + threadIdx.x;
  if (i >= total4) return;
  size_t o = (size_t)i * 4;
  uint2 v1 = *(const uint2*)(x1 + o), v2 = *(const uint2*)(x2 + o);
  uint2 v3 = *(const uint2*)(x3 + o), v4 = *(const uint2*)(x4 + o);
  float a1[4] = {bl(v1.x), bh(v1.x), bl(v1.y), bh(v1.y)};
  float a2[4] = {bl(v2.x), bh(v2.x), bl(v2.y), bh(v2.y)};
  float a3[4] = {bl(v3.x), bh(v3.x), bl(v3.y), bh(v3.y)};
  float a4[4] = {bl(v4.x), bh(v4.x), bl(v4.y), bh(v4.y)};
  float y2[4], y3[4], y4[4];
#pragma unroll
  for (int j = 0; j < 4; ++j) {
    y2[j] = a2[j] + a1[j];
    y3[j] = a3[j] + y2[j];
    y4[j] = a4[j] + y3[j];
  }
  *(uint2*)(x2 + o) = uint2{pk2(y2[0], y2[1]), pk2(y2[2], y2[3])};
  *(uint2*)(x3 + o) = uint2{pk2(y3[0], y3[1]), pk2(y3[2], y3[3])};
  *(uint2*)(x4 + o) = uint2{pk2(y4[0], y4[1]), pk2(y4[2], y4[3])};
}

// ---------- s = 1.4*(x1+x2+x3+x4) + 0.25*hsum  (hsum bf16) ----------
__global__ __launch_bounds__(256) void k_sfin(const u16* __restrict__ x1, const u16* __restrict__ x2,
                                              const u16* __restrict__ x3, const u16* __restrict__ x4,
                                              const u16* __restrict__ hsum, u16* __restrict__ sb,
                                              int total4) {
  int i = blockIdx.x * 256 + threadIdx.x;
  if (i >= total4) return;
  size_t o = (size_t)i * 4;
  uint2 v1 = *(const uint2*)(x1 + o), v2 = *(const uint2*)(x2 + o);
  uint2 v3 = *(const uint2*)(x3 + o), v4 = *(const uint2*)(x4 + o);
  uint2 vh = *(const uint2*)(hsum + o);
  float hh[4] = {bl(vh.x), bh(vh.x), bl(vh.y), bh(vh.y)};
  float r0 = 1.4f * (bl(v1.x) + bl(v2.x) + bl(v3.x) + bl(v4.x)) + 0.25f * hh[0];
  float r1 = 1.4f * (bh(v1.x) + bh(v2.x) + bh(v3.x) + bh(v4.x)) + 0.25f * hh[1];
  float r2 = 1.4f * (bl(v1.y) + bl(v2.y) + bl(v3.y) + bl(v4.y)) + 0.25f * hh[2];
  float r3 = 1.4f * (bh(v1.y) + bh(v2.y) + bh(v3.y) + bh(v4.y)) + 0.25f * hh[3];
  *(uint2*)(sb + o) = uint2{pk2(r0, r1), pk2(r2, r3)};
}

extern "C" void kernel_launch(void* const* d_in, const int* in_sizes, int n_in,
                              void* d_out, int out_size, void* d_ws, size_t ws_size,
                              hipStream_t stream) {
  (void)n_in; (void)out_size;
  const int N = in_sizes[0] / 512;          // 50000
  const int E = in_sizes[1] / 2;            // 800000
  const int Mpad = ((N + 255) / 256) * 256; // 50176 (mult of 256 for BM=256 LSTM tiles)
  auto al128 = [](int v) { return ((v + 127) / 128) * 128; };

  const float* x = (const float*)d_in[0];
  const int* ei = (const int*)d_in[1];
  const int* esrc_in = ei;
  const int* edst_in = ei + E;

  // ---- workspace arena ----
  size_t off = 0;
  auto alloc = [&](size_t bytes) { size_t o = off; off += (bytes + 255) & ~(size_t)255; return o; };
  char* ws = (char*)d_ws;
  const size_t szH = (size_t)Mpad * 256 * 2;   // 25.7 MB
  const size_t szXB = (size_t)Mpad * 512 * 2;  // 51.4 MB
  const int widx[13] = {2, 4, 6, 8, 10, 12, 14, 16, 18, 19, 21, 22, 24};
  const int wK[13] = {512, 256, 256, 256, 256, 256, 256, 256, 256, 256, 256, 256, 256};
  const int wN[13] = {256, 256, 256, 256, 256, 256, 256, 256, 1024, 1024, 1024, 1024, 256};
  size_t wt_o[13];
  for (int i = 0; i < 13; ++i) wt_o[i] = alloc((size_t)wK[i] * wN[i] * 2);
  size_t rowstart_o = alloc((size_t)(N + 1) * 4);
  size_t cursor_o = alloc((size_t)N * 4);
  size_t bsum_o = alloc(256 * 4);
  size_t esrc_o = alloc((size_t)E * 4);
  size_t x_o[4];
  for (int t = 0; t < 4; ++t) x_o[t] = alloc(szH);
  // tmp union region:
  //  conv phase:  [xb szXB][y1 szH][z McC*512]
  //  lstm phase:  [h0s x4][h1p x2][cst][sbc][hsum] all bf16 = McL*4608 B  (9 x 512B/row)
  int McC = al128((Mpad + 3) / 4);
  int McL = Mpad;
  {
    const int ccand[3] = {Mpad, al128((Mpad + 1) / 2), al128((Mpad + 3) / 4)};
    const int lcand[5] = {Mpad, 25088, 16384, 8192, 6400};  // all multiples of 256
    bool done = false;
    for (int ci = 0; ci < 3 && !done; ++ci) {
      for (int li = 0; li < 5 && !done; ++li) {
        size_t cneed = szXB + szH + (size_t)ccand[ci] * 512;
        size_t lneed = (size_t)lcand[li] * 4608;
        size_t tmp = cneed > lneed ? cneed : lneed;
        if (off + tmp + (1u << 20) <= ws_size) { McC = ccand[ci]; McL = lcand[li]; done = true; }
      }
    }
  }
  const size_t hb = (size_t)McL * 256 * 2;
  size_t lstm_sz = 9 * hb;
  size_t conv_sz = szXB + szH + (size_t)McC * 512;
  size_t tmp_o = alloc(lstm_sz > conv_sz ? lstm_sz : conv_sz);
  if (off > ws_size) return;

  u16* wt[13];
  for (int i = 0; i < 13; ++i) wt[i] = (u16*)(ws + wt_o[i]);
  int* rowstart = (int*)(ws + rowstart_o);
  int* cursor = (int*)(ws + cursor_o);
  int* bsum = (int*)(ws + bsum_o);
  int* esrc = (int*)(ws + esrc_o);
  u16* xl[4];
  for (int t = 0; t < 4; ++t) xl[t] = (u16*)(ws + x_o[t]);
  // conv views
  u16* xb = (u16*)(ws + tmp_o);
  u16* y1 = (u16*)(ws + tmp_o + szXB);
  u16* zC = (u16*)(ws + tmp_o + szXB + szH);
  // lstm views (overlay same region; conv temps dead by then)
  u16* h0s[4];
  for (int t = 0; t < 4; ++t) h0s[t] = (u16*)(ws + tmp_o + t * hb);
  u16* h1p[2] = {(u16*)(ws + tmp_o + 4 * hb), (u16*)(ws + tmp_o + 5 * hb)};
  u16* cst = (u16*)(ws + tmp_o + 6 * hb);
  u16* sbc = (u16*)(ws + tmp_o + 7 * hb);
  u16* hsum = (u16*)(ws + tmp_o + 8 * hb);

  // ---- weight prep + x->bf16 (pad rows zeroed) ----
  WTargs wa;
  int bacc = 0;
  for (int i = 0; i < 13; ++i) {
    wa.src[i] = (const float*)d_in[widx[i]];
    wa.dst[i] = wt[i];
    wa.K[i] = wK[i];
    wa.Nc[i] = wN[i];
    wa.bstart[i] = bacc;
    bacc += (wK[i] * wN[i] + 255) / 256;
  }
  wa.bstart[13] = bacc;
  k_wtall<<<bacc, 256, 0, stream>>>(wa);
  k_x2bf<<<(N * 64 + 255) / 256, 256, 0, stream>>>(x, xb, N * 64);
  if (Mpad > N) hipMemsetAsync(xb + (size_t)N * 512, 0, (size_t)(Mpad - N) * 512 * 2, stream);
  // ---- CSR (hierarchical scan) ----
  hipMemsetAsync(cursor, 0, (size_t)N * 4, stream);
  k_hist<<<(E + 255) / 256, 256, 0, stream>>>(edst_in, cursor, E);
  const int nb = (N + 1023) / 1024;
  k_scan1<<<nb, 1024, 0, stream>>>(cursor, rowstart, bsum, N);
  k_scan2<<<1, 64, 0, stream>>>(bsum, nb);
  k_scan3<<<(N + 255) / 256, 256, 0, stream>>>(bsum, rowstart, cursor, N);
  k_scatter<<<(E + 255) / 256, 256, 0, stream>>>(esrc_in, edst_in, cursor, esrc, E);

  // mode: 0 = bf16-out (128x128), 1 = relu bf16-out (128x128), 2 = relu fp32-out (128x64)
  auto gemm = [&](const u16* A1, const u16* B1, int K1, const u16* A2, const u16* B2, int K2,
                  const float* bias, float bscale, void* out, int Nout, int rows, int Mstore,
                  int mode) {
    dim3 b(256);
    if (mode == 0) {
      int NT = Nout / 128;
      dim3 g((rows / 128) * NT);
      k_gemm<128, 128, 0><<<g, b, 0, stream>>>(A1, B1, K1, A2, B2, K2, bias, bscale, out, Nout,
                                               Mstore, NT, nullptr, nullptr, 0, 0);
    } else if (mode == 1) {
      int NT = Nout / 128;
      dim3 g((rows / 128) * NT);
      k_gemm<128, 128, 1><<<g, b, 0, stream>>>(A1, B1, K1, A2, B2, K2, bias, bscale, out, Nout,
                                               Mstore, NT, nullptr, nullptr, 0, 0);
    } else {
      int NT = Nout / 64;
      dim3 g((rows / 128) * NT);
      k_gemm<128, 64, 2><<<g, b, 0, stream>>>(A1, B1, K1, A2, B2, K2, bias, bscale, out, Nout,
                                              Mstore, NT, nullptr, nullptr, 0, 0);
    }
  };
  // fused LSTM step: BM=256 tile (doubles MFMA per barrier pair), gate-sliced B, bf16 c/hsum
  auto lstm_step = [&](const u16* xt, const u16* wih, const u16* hprev, const u16* whh,
                       const float* bias, u16* hout, u16* hsumP, int rows, int first, int dosum) {
    dim3 g((rows / 256) * 8), b(256);
    k_gemm<256, 128, 3><<<g, b, 0, stream>>>(xt, wih, 256, hprev, whh, 256, bias, 1.f,
                                             hout, 256, rows, 8, cst, hsumP, first, dosum);
  };

  // ---- conv1 via linearity: y1 = xb@W1 (no bias); z = relu(gather(y1)+b1); x1 = relu(z@W2+b2) ----
  gemm(xb, wt[0], 512, nullptr, nullptr, 0, nullptr, 0.f, y1, 256, Mpad, Mpad, 0);
  for (int base = 0; base < Mpad; base += McC) {
    int rows = Mpad - base < McC ? Mpad - base : McC;
    int ab = (rows + 3) / 4;
    k_aggbr<<<ab, 256, 0, stream>>>(y1, rowstart, esrc, (const float*)d_in[3], zC, N, base, rows);
    gemm(zC, wt[1], 256, nullptr, nullptr, 0, (const float*)d_in[5], 1.f,
         xl[0] + (size_t)base * 256, 256, rows, rows, 1);
  }
  // ---- conv2-4 (h-space gather) ----
  for (int l = 1; l < 4; ++l) {
    const int cb1[4] = {3, 7, 11, 15}, cb2[4] = {5, 9, 13, 17};
    for (int base = 0; base < Mpad; base += McC) {
      int rows = Mpad - base < McC ? Mpad - base : McC;
      int ab = (rows + 3) / 4;
      k_agg256<<<ab, 256, 0, stream>>>(xl[l - 1], rowstart, esrc, zC, N, base, rows);
      gemm((u16*)zC, wt[2 * l], 256, nullptr, nullptr, 0, (const float*)d_in[cb1[l]], 1.f,
           y1, 256, rows, rows, 1);
      gemm(y1, wt[2 * l + 1], 256, nullptr, nullptr, 0, (const float*)d_in[cb2[l]], 1.f,
           xl[l] + (size_t)base * 256, 256, rows, rows, 1);
    }
  }
  // ---- residual cascade in place ----
  k_cascade<<<(Mpad * 64 + 255) / 256, 256, 0, stream>>>(xl[0], xl[1], xl[2], xl[3], Mpad * 64);

  // ---- LSTM + final (gates fused, gate-sliced tiles, bf16 c/hsum, BM=256) ----
  const float* b_l0 = (const float*)d_in[20];
  const float* b_l1 = (const float*)d_in[23];
  const float* b_mlp = (const float*)d_in[25];
  for (int base = 0; base < Mpad; base += McL) {
    int rows = Mpad - base < McL ? Mpad - base : McL;
    const size_t boff = (size_t)base * 256;
    for (int t = 0; t < 4; ++t)  // layer 0
      lstm_step(xl[t] + boff, wt[8], t ? h0s[t - 1] : nullptr, wt[9], b_l0,
                h0s[t], nullptr, rows, t == 0, 0);
    for (int t = 0; t < 4; ++t)  // layer 1 (accumulate hsum)
      lstm_step(h0s[t], wt[10], t ? h1p[(t + 1) & 1] : nullptr, wt[11], b_l1,
                h1p[t & 1], hsum, rows, t == 0, 1);
    k_sfin<<<(rows * 64 + 255) / 256, 256, 0, stream>>>(xl[0] + boff, xl[1] + boff, xl[2] + boff,
                                                        xl[3] + boff, hsum, sbc, rows * 64);
    int st = N - base;
    if (st > rows) st = rows;
    if (st > 0)
      gemm(sbc, wt[12], 256, nullptr, nullptr, 0, b_mlp, 3.f,
           (float*)d_out + boff, 256, rows, st, 2);
  }
}

// Round 18
// 1435.653 us; speedup vs baseline: 1.6277x; 1.6277x over previous
//
#include <hip/hip_runtime.h>

typedef unsigned int u32;
typedef unsigned short u16;

typedef __attribute__((ext_vector_type(8))) __bf16 bf16x8;
typedef __attribute__((ext_vector_type(4))) float f32x4;

__device__ __forceinline__ u16 f2bf(float f) {
  u32 u = __float_as_uint(f);
  u += 0x7fffu + ((u >> 16) & 1u);
  return (u16)(u >> 16);
}
__device__ __forceinline__ float bl(u32 u) { return __uint_as_float(u << 16); }
__device__ __forceinline__ float bh(u32 u) { return __uint_as_float(u & 0xffff0000u); }
__device__ __forceinline__ u32 pk2(float a, float b) { return (u32)f2bf(a) | ((u32)f2bf(b) << 16); }
__device__ __forceinline__ float fsig(float x) { return 1.f / (1.f + __expf(-x)); }
__device__ __forceinline__ float ftanh(float x) { return 1.f - 2.f / (__expf(2.f * x) + 1.f); }

#define GLDS16(gp, lp)                                                                  \
  __builtin_amdgcn_global_load_lds((const __attribute__((address_space(1))) u32*)(gp),  \
                                   (__attribute__((address_space(3))) u32*)(lp), 16, 0, 0)

// ---------- batched weight transpose+cast: wt[c*K+k] = bf16(w[k*N+c]) ----------
struct WTargs {
  const float* src[13];
  u16* dst[13];
  int K[13];
  int Nc[13];
  int bstart[14];
};
__global__ __launch_bounds__(256) void k_wtall(WTargs wa) {
  int b = blockIdx.x;
  int w = 0;
  while (b >= wa.bstart[w + 1]) ++w;
  int i = (b - wa.bstart[w]) * 256 + threadIdx.x;
  int K = wa.K[w], Nc = wa.Nc[w];
  if (i >= K * Nc) return;
  int k = i / Nc, c = i - k * Nc;
  wa.dst[w][(size_t)c * K + k] = f2bf(wa.src[w][i]);
}

// ---------- x fp32 [N,512] -> bf16 xb ----------
__global__ __launch_bounds__(256) void k_x2bf(const float* __restrict__ x, u16* __restrict__ xb, int total8) {
  int i = blockIdx.x * 256 + threadIdx.x;
  if (i >= total8) return;
  size_t o = (size_t)i * 8;
  float4 a = *(const float4*)(x + o), b = *(const float4*)(x + o + 4);
  uint4 v;
  v.x = pk2(a.x, a.y); v.y = pk2(a.z, a.w); v.z = pk2(b.x, b.y); v.w = pk2(b.z, b.w);
  *(uint4*)(xb + o) = v;
}

// ---------- CSR build ----------
__global__ void k_hist(const int* __restrict__ dst, int* __restrict__ deg, int E) {
  int e = blockIdx.x * 256 + threadIdx.x;
  if (e < E) atomicAdd(&deg[dst[e]], 1);
}
__global__ __launch_bounds__(1024) void k_scan1(const int* __restrict__ deg, int* __restrict__ rs,
                                                int* __restrict__ bsum, int n) {
  __shared__ int buf[1024];
  int t = threadIdx.x, idx = blockIdx.x * 1024 + t;
  int v = idx < n ? deg[idx] : 0;
  buf[t] = v;
  __syncthreads();
  for (int off = 1; off < 1024; off <<= 1) {
    int u = t >= off ? buf[t - off] : 0;
    __syncthreads();
    buf[t] += u;
    __syncthreads();
  }
  if (idx < n) rs[idx + 1] = buf[t];
  if (t == 1023) bsum[blockIdx.x] = buf[1023];
}
__global__ void k_scan2(int* bsum, int nb) {
  if (threadIdx.x == 0) {
    int s = 0;
    for (int b = 0; b < nb; ++b) { s += bsum[b]; bsum[b] = s; }
  }
}
__global__ void k_scan3(const int* __restrict__ bsum, int* __restrict__ rs,
                        int* __restrict__ cursor, int n) {
  int i = blockIdx.x * 256 + threadIdx.x;
  if (i >= n) return;
  int b = i >> 10;
  int add = b ? bsum[b - 1] : 0;
  int v = rs[i + 1] + add;  // inclusive prefix
  int d = cursor[i];        // deg
  rs[i + 1] = v;
  cursor[i] = v - d;        // exclusive prefix = scatter cursor
  if (i == 0) rs[0] = 0;
}
__global__ void k_scatter(const int* __restrict__ src, const int* __restrict__ dst,
                          int* __restrict__ cursor, int* __restrict__ esrc, int E) {
  int e = blockIdx.x * 256 + threadIdx.x;
  if (e < E) {
    int p = atomicAdd(&cursor[dst[e]], 1);
    esrc[p] = src[e];
  }
}

// ---------- conv1 projected-space gather: z = relu(y[node] + sum_nb y[src] + b1) ----------
__global__ __launch_bounds__(256) void k_aggbr(const u16* __restrict__ y, const int* __restrict__ rowstart,
                                               const int* __restrict__ esrc, const float* __restrict__ b1,
                                               u16* __restrict__ z, int Nn, int base, int rows) {
  int lane = threadIdx.x & 63, wid = threadIdx.x >> 6;
  int r = blockIdx.x * 4 + wid;
  if (r >= rows) return;
  int node = base + r;
  const int cb = lane * 4;
  u16* orow = z + (size_t)r * 256 + cb;
  if (node >= Nn) { *(uint2*)orow = uint2{0, 0}; return; }
  float acc[4];
  {
    uint2 v = *(const uint2*)(y + (size_t)node * 256 + cb);
    acc[0] = bl(v.x); acc[1] = bh(v.x); acc[2] = bl(v.y); acc[3] = bh(v.y);
  }
  int s = rowstart[node], e = rowstart[node + 1];
  int j = s;
  for (; j + 3 < e; j += 4) {
    uint2 v0 = *(const uint2*)(y + (size_t)esrc[j] * 256 + cb);
    uint2 v1 = *(const uint2*)(y + (size_t)esrc[j + 1] * 256 + cb);
    uint2 v2 = *(const uint2*)(y + (size_t)esrc[j + 2] * 256 + cb);
    uint2 v3 = *(const uint2*)(y + (size_t)esrc[j + 3] * 256 + cb);
    acc[0] += (bl(v0.x) + bl(v1.x)) + (bl(v2.x) + bl(v3.x));
    acc[1] += (bh(v0.x) + bh(v1.x)) + (bh(v2.x) + bh(v3.x));
    acc[2] += (bl(v0.y) + bl(v1.y)) + (bl(v2.y) + bl(v3.y));
    acc[3] += (bh(v0.y) + bh(v1.y)) + (bh(v2.y) + bh(v3.y));
  }
  for (; j < e; ++j) {
    uint2 v = *(const uint2*)(y + (size_t)esrc[j] * 256 + cb);
    acc[0] += bl(v.x); acc[1] += bh(v.x); acc[2] += bl(v.y); acc[3] += bh(v.y);
  }
  float4 bb = *(const float4*)(b1 + cb);
  acc[0] = fmaxf(acc[0] + bb.x, 0.f);
  acc[1] = fmaxf(acc[1] + bb.y, 0.f);
  acc[2] = fmaxf(acc[2] + bb.z, 0.f);
  acc[3] = fmaxf(acc[3] + bb.w, 0.f);
  uint2 o;
  o.x = pk2(acc[0], acc[1]); o.y = pk2(acc[2], acc[3]);
  *(uint2*)orow = o;
}

// ---------- conv2-4 aggregation from bf16 h [Mpad,256] ----------
__global__ __launch_bounds__(256) void k_agg256(const u16* __restrict__ h,
                                                const int* __restrict__ rowstart,
                                                const int* __restrict__ esrc,
                                                u16* __restrict__ out, int Nn, int base, int rows) {
  int lane = threadIdx.x & 63, wid = threadIdx.x >> 6;
  int r = blockIdx.x * 4 + wid;
  if (r >= rows) return;
  int node = base + r;
  const int cb = lane * 4;
  u16* orow = out + (size_t)r * 256 + cb;
  if (node >= Nn) { *(uint2*)orow = uint2{0, 0}; return; }
  float acc[4];
  {
    uint2 v = *(const uint2*)(h + (size_t)node * 256 + cb);
    acc[0] = bl(v.x); acc[1] = bh(v.x); acc[2] = bl(v.y); acc[3] = bh(v.y);
  }
  int s = rowstart[node], e = rowstart[node + 1];
  int j = s;
  for (; j + 3 < e; j += 4) {
    uint2 v0 = *(const uint2*)(h + (size_t)esrc[j] * 256 + cb);
    uint2 v1 = *(const uint2*)(h + (size_t)esrc[j + 1] * 256 + cb);
    uint2 v2 = *(const uint2*)(h + (size_t)esrc[j + 2] * 256 + cb);
    uint2 v3 = *(const uint2*)(h + (size_t)esrc[j + 3] * 256 + cb);
    acc[0] += (bl(v0.x) + bl(v1.x)) + (bl(v2.x) + bl(v3.x));
    acc[1] += (bh(v0.x) + bh(v1.x)) + (bh(v2.x) + bh(v3.x));
    acc[2] += (bl(v0.y) + bl(v1.y)) + (bl(v2.y) + bl(v3.y));
    acc[3] += (bh(v0.y) + bh(v1.y)) + (bh(v2.y) + bh(v3.y));
  }
  for (; j < e; ++j) {
    uint2 v = *(const uint2*)(h + (size_t)esrc[j] * 256 + cb);
    acc[0] += bl(v.x); acc[1] += bh(v.x); acc[2] += bl(v.y); acc[3] += bh(v.y);
  }
  uint2 o;
  o.x = pk2(acc[0], acc[1]); o.y = pk2(acc[2], acc[3]);
  *(uint2*)orow = o;
}

// ---------- bf16 MFMA GEMM (round-16-proven): glds staging + XOR-swizzled LDS + XCD swizzle ----------
// Single-buffered LDS, __syncthreads-paced. 128xBN tile, BK=64, 4 waves 2x2 — the occupancy/density
// sweet spot: deeper pipelines (r15) and bigger tiles (r17) both regressed via lost blocks/CU.
// MODE 0: bf16 out, 1: relu bf16 out, 2: relu fp32 out; MODE 3: fused LSTM gates
// (gate-sliced B tiles; c-state bf16).
template <int BN, int MODE>
__global__ __launch_bounds__(256) void k_gemm(const u16* __restrict__ A1, const u16* __restrict__ B1, int K1,
                                              const u16* __restrict__ A2, const u16* __restrict__ B2, int K2,
                                              const float* __restrict__ bias, float bscale,
                                              void* __restrict__ outp, int Nout, int Mstore, int NT,
                                              u16* __restrict__ cstp, float* __restrict__ hsump,
                                              int first, int dosum) {
  constexpr int NF = BN / 32;
  __shared__ u16 Al[128 * 64];
  __shared__ u16 Bl[BN * 64];
  const int tid = threadIdx.x;
  const int lane = tid & 63, wid = tid >> 6;
  const int wr = wid >> 1, wc = wid & 1;
  // bijective XCD swizzle (m204)
  const int nwg = gridDim.x;
  const int orig = blockIdx.x;
  const int q = nwg >> 3, rr8 = nwg & 7;
  const int xcd = orig & 7;
  const int wgid = (xcd < rr8 ? xcd * (q + 1) : rr8 * (q + 1) + (xcd - rr8) * q) + (orig >> 3);
  const int mtile = wgid / NT, ntile = wgid - mtile * NT;
  const int m0 = mtile * 128;
  const int n0 = ntile * BN;       // MODE<3 column base
  const int h0 = ntile * 32;       // MODE==3 hcol base
  const int l15 = lane & 15, l4 = lane >> 4;
  const int srow = lane >> 3;
  const int scol = ((lane & 7) ^ (lane >> 3)) * 8;  // pre-swizzled global column slot
  const int rsw = l15 & 7;                          // read-side row XOR key
  f32x4 acc[4][NF] = {};

  for (int s = 0; s < 2; ++s) {
    const u16* A = s ? A2 : A1;
    const u16* B = s ? B2 : B1;
    const int K = s ? K2 : K1;
    if (A == nullptr) continue;
    for (int k0 = 0; k0 < K; k0 += 64) {
      __syncthreads();  // previous tile's LDS reads done before overwrite
#pragma unroll
      for (int p = 0; p < 4; ++p) {
        int r = m0 + p * 32 + wid * 8 + srow;
        GLDS16(A + (size_t)r * K + k0 + scol, &Al[(p * 32 + wid * 8) * 64]);
      }
#pragma unroll
      for (int p = 0; p < NF; ++p) {
        int r;
        if constexpr (MODE == 3) r = p * 256 + h0 + wid * 8 + srow;  // gate p rows
        else r = n0 + p * 32 + wid * 8 + srow;
        GLDS16(B + (size_t)r * K + k0 + scol, &Bl[(p * 32 + wid * 8) * 64]);
      }
      __syncthreads();  // compiler drains vmcnt before barrier
#pragma unroll
      for (int ks = 0; ks < 2; ++ks) {
        const int sp = (((ks * 4 + l4) ^ rsw)) * 8;  // swizzled 16B-slot within row
        bf16x8 af[4], bfr[NF];
#pragma unroll
        for (int m = 0; m < 4; ++m)
          af[m] = *(const bf16x8*)&Al[(wr * 64 + m * 16 + l15) * 64 + sp];
#pragma unroll
        for (int n = 0; n < NF; ++n) {
          int trow;
          if constexpr (MODE == 3) trow = n * 32 + wc * 16 + l15;  // gate n, hcol subset
          else trow = wc * (BN / 2) + n * 16 + l15;
          bfr[n] = *(const bf16x8*)&Bl[trow * 64 + sp];
        }
#pragma unroll
        for (int m = 0; m < 4; ++m)
#pragma unroll
          for (int n = 0; n < NF; ++n)
            acc[m][n] = __builtin_amdgcn_mfma_f32_16x16x32_bf16(af[m], bfr[n], acc[m][n], 0, 0, 0);
      }
    }
  }

  if constexpr (MODE == 3) {
    const int hcol = h0 + wc * 16 + l15;
    const float bi = bias[hcol], bf2 = bias[256 + hcol];
    const float bg = bias[512 + hcol], bo = bias[768 + hcol];
    u16* hout = (u16*)outp;
#pragma unroll
    for (int m = 0; m < 4; ++m) {
      int gr0 = m0 + wr * 64 + m * 16 + l4 * 4;
#pragma unroll
      for (int r = 0; r < 4; ++r) {
        int gr = gr0 + r;
        if (gr >= Mstore) continue;
        float gi = acc[m][0][r] + bi;
        float gf = acc[m][1][r] + bf2;
        float gg = acc[m][2][r] + bg;
        float go = acc[m][3][r] + bo;
        size_t o = (size_t)gr * 256 + hcol;
        float nc = fsig(gi) * ftanh(gg);
        if (!first) nc += fsig(gf) * bl((u32)cstp[o]);
        cstp[o] = f2bf(nc);
        nc = bl((u32)f2bf(nc));  // use stored-precision c for h (consistency)
        float h = fsig(go) * ftanh(nc);
        hout[o] = f2bf(h);
        if (dosum) {
          if (first) hsump[o] = h;
          else hsump[o] += h;
        }
      }
    }
    return;
  }

#pragma unroll
  for (int m = 0; m < 4; ++m) {
    int gr0 = m0 + wr * 64 + m * 16 + l4 * 4;
#pragma unroll
    for (int n = 0; n < NF; ++n) {
      int gc = n0 + wc * (BN / 2) + n * 16 + l15;
      float bb = bias ? bias[gc] * bscale : 0.f;
#pragma unroll
      for (int r = 0; r < 4; ++r) {
        int gr = gr0 + r;
        if (gr >= Mstore) continue;
        float v = acc[m][n][r] + bb;
        if (MODE >= 1) v = fmaxf(v, 0.f);
        if (MODE == 2) ((float*)outp)[(size_t)gr * Nout + gc] = v;
        else ((u16*)outp)[(size_t)gr * Nout + gc] = f2bf(v);
      }
    }
  }
}

// ---------- residual cascade in place ----------
__global__ __launch_bounds__(256) void k_cascade(const u16* __restrict__ x1, u16* __restrict__ x2,
                                                 u16* __restrict__ x3, u16* __restrict__ x4, int total4) {
  int i = blockIdx.x * 256 + threadIdx.x;
  if (i >= total4) return;
  size_t o = (size_t)i * 4;
  uint2 v1 = *(const uint2*)(x1 + o), v2 = *(const uint2*)(x2 + o);
  uint2 v3 = *(const uint2*)(x3 + o), v4 = *(const uint2*)(x4 + o);
  float a1[4] = {bl(v1.x), bh(v1.x), bl(v1.y), bh(v1.y)};
  float a2[4] = {bl(v2.x), bh(v2.x), bl(v2.y), bh(v2.y)};
  float a3[4] = {bl(v3.x), bh(v3.x), bl(v3.y), bh(v3.y)};
  float a4[4] = {bl(v4.x), bh(v4.x), bl(v4.y), bh(v4.y)};
  float y2[4], y3[4], y4[4];
#pragma unroll
  for (int j = 0; j < 4; ++j) {
    y2[j] = a2[j] + a1[j];
    y3[j] = a3[j] + y2[j];
    y4[j] = a4[j] + y3[j];
  }
  *(uint2*)(x2 + o) = uint2{pk2(y2[0], y2[1]), pk2(y2[2], y2[3])};
  *(uint2*)(x3 + o) = uint2{pk2(y3[0], y3[1]), pk2(y3[2], y3[3])};
  *(uint2*)(x4 + o) = uint2{pk2(y4[0], y4[1]), pk2(y4[2], y4[3])};
}

// ---------- s = 1.4*(x1+x2+x3+x4) + 0.25*hsum ----------
__global__ __launch_bounds__(256) void k_sfin(const u16* __restrict__ x1, const u16* __restrict__ x2,
                                              const u16* __restrict__ x3, const u16* __restrict__ x4,
                                              const float* __restrict__ hsum, u16* __restrict__ sb,
                                              int total4) {
  int i = blockIdx.x * 256 + threadIdx.x;
  if (i >= total4) return;
  size_t o = (size_t)i * 4;
  uint2 v1 = *(const uint2*)(x1 + o), v2 = *(const uint2*)(x2 + o);
  uint2 v3 = *(const uint2*)(x3 + o), v4 = *(const uint2*)(x4 + o);
  float4 hh = *(const float4*)(hsum + o);
  float r0 = 1.4f * (bl(v1.x) + bl(v2.x) + bl(v3.x) + bl(v4.x)) + 0.25f * hh.x;
  float r1 = 1.4f * (bh(v1.x) + bh(v2.x) + bh(v3.x) + bh(v4.x)) + 0.25f * hh.y;
  float r2 = 1.4f * (bl(v1.y) + bl(v2.y) + bl(v3.y) + bl(v4.y)) + 0.25f * hh.z;
  float r3 = 1.4f * (bh(v1.y) + bh(v2.y) + bh(v3.y) + bh(v4.y)) + 0.25f * hh.w;
  *(uint2*)(sb + o) = uint2{pk2(r0, r1), pk2(r2, r3)};
}

extern "C" void kernel_launch(void* const* d_in, const int* in_sizes, int n_in,
                              void* d_out, int out_size, void* d_ws, size_t ws_size,
                              hipStream_t stream) {
  (void)n_in; (void)out_size;
  const int N = in_sizes[0] / 512;          // 50000
  const int E = in_sizes[1] / 2;            // 800000
  const int Mpad = ((N + 127) / 128) * 128; // 50176
  auto al128 = [](int v) { return ((v + 127) / 128) * 128; };

  const float* x = (const float*)d_in[0];
  const int* ei = (const int*)d_in[1];
  const int* esrc_in = ei;
  const int* edst_in = ei + E;

  // ---- workspace arena ----
  size_t off = 0;
  auto alloc = [&](size_t bytes) { size_t o = off; off += (bytes + 255) & ~(size_t)255; return o; };
  char* ws = (char*)d_ws;
  const size_t szH = (size_t)Mpad * 256 * 2;   // 25.7 MB
  const size_t szXB = (size_t)Mpad * 512 * 2;  // 51.4 MB
  const int widx[13] = {2, 4, 6, 8, 10, 12, 14, 16, 18, 19, 21, 22, 24};
  const int wK[13] = {512, 256, 256, 256, 256, 256, 256, 256, 256, 256, 256, 256, 256};
  const int wN[13] = {256, 256, 256, 256, 256, 256, 256, 256, 1024, 1024, 1024, 1024, 256};
  size_t wt_o[13];
  for (int i = 0; i < 13; ++i) wt_o[i] = alloc((size_t)wK[i] * wN[i] * 2);
  size_t rowstart_o = alloc((size_t)(N + 1) * 4);
  size_t cursor_o = alloc((size_t)N * 4);
  size_t bsum_o = alloc(256 * 4);
  size_t esrc_o = alloc((size_t)E * 4);
  size_t x_o[4];
  for (int t = 0; t < 4; ++t) x_o[t] = alloc(szH);
  // tmp union region:
  //  conv phase:  [xb szXB][y1 szH][z McC*512]
  //  lstm phase:  [h0s x4][h1p x2][cst bf16][sbc][hsum fp32]  = McL*5120 B
  int McC = al128((Mpad + 3) / 4);
  int McL = al128((Mpad + 7) / 8);
  {
    const int ccand[3] = {Mpad, al128((Mpad + 1) / 2), al128((Mpad + 3) / 4)};
    const int lcand[5] = {Mpad, al128((Mpad + 1) / 2), 16384, 8192, al128((Mpad + 7) / 8)};
    bool done = false;
    for (int ci = 0; ci < 3 && !done; ++ci) {
      for (int li = 0; li < 5 && !done; ++li) {
        size_t cneed = szXB + szH + (size_t)ccand[ci] * 512;
        size_t lneed = (size_t)lcand[li] * 5120;
        size_t tmp = cneed > lneed ? cneed : lneed;
        if (off + tmp + (1u << 20) <= ws_size) { McC = ccand[ci]; McL = lcand[li]; done = true; }
      }
    }
  }
  const size_t hb = (size_t)McL * 256 * 2;
  const size_t fb = (size_t)McL * 256 * 4;
  size_t lstm_sz = 8 * hb + fb;
  size_t conv_sz = szXB + szH + (size_t)McC * 512;
  size_t tmp_o = alloc(lstm_sz > conv_sz ? lstm_sz : conv_sz);
  if (off > ws_size) return;

  u16* wt[13];
  for (int i = 0; i < 13; ++i) wt[i] = (u16*)(ws + wt_o[i]);
  int* rowstart = (int*)(ws + rowstart_o);
  int* cursor = (int*)(ws + cursor_o);
  int* bsum = (int*)(ws + bsum_o);
  int* esrc = (int*)(ws + esrc_o);
  u16* xl[4];
  for (int t = 0; t < 4; ++t) xl[t] = (u16*)(ws + x_o[t]);
  // conv views
  u16* xb = (u16*)(ws + tmp_o);
  u16* y1 = (u16*)(ws + tmp_o + szXB);
  u16* zC = (u16*)(ws + tmp_o + szXB + szH);
  // lstm views (overlay same region; conv temps dead by then)
  u16* h0s[4];
  for (int t = 0; t < 4; ++t) h0s[t] = (u16*)(ws + tmp_o + t * hb);
  u16* h1p[2] = {(u16*)(ws + tmp_o + 4 * hb), (u16*)(ws + tmp_o + 5 * hb)};
  u16* cst = (u16*)(ws + tmp_o + 6 * hb);
  u16* sbc = (u16*)(ws + tmp_o + 7 * hb);
  float* hsum = (float*)(ws + tmp_o + 8 * hb);

  // ---- weight prep + x->bf16 (pad rows zeroed) ----
  WTargs wa;
  int bacc = 0;
  for (int i = 0; i < 13; ++i) {
    wa.src[i] = (const float*)d_in[widx[i]];
    wa.dst[i] = wt[i];
    wa.K[i] = wK[i];
    wa.Nc[i] = wN[i];
    wa.bstart[i] = bacc;
    bacc += (wK[i] * wN[i] + 255) / 256;
  }
  wa.bstart[13] = bacc;
  k_wtall<<<bacc, 256, 0, stream>>>(wa);
  k_x2bf<<<(N * 64 + 255) / 256, 256, 0, stream>>>(x, xb, N * 64);
  if (Mpad > N) hipMemsetAsync(xb + (size_t)N * 512, 0, (size_t)(Mpad - N) * 512 * 2, stream);
  // ---- CSR (hierarchical scan) ----
  hipMemsetAsync(cursor, 0, (size_t)N * 4, stream);
  k_hist<<<(E + 255) / 256, 256, 0, stream>>>(edst_in, cursor, E);
  const int nb = (N + 1023) / 1024;
  k_scan1<<<nb, 1024, 0, stream>>>(cursor, rowstart, bsum, N);
  k_scan2<<<1, 64, 0, stream>>>(bsum, nb);
  k_scan3<<<(N + 255) / 256, 256, 0, stream>>>(bsum, rowstart, cursor, N);
  k_scatter<<<(E + 255) / 256, 256, 0, stream>>>(esrc_in, edst_in, cursor, esrc, E);

  // mode: 0 = bf16-out (BN=128), 1 = relu bf16-out (BN=128), 2 = relu fp32-out (BN=64)
  auto gemm = [&](const u16* A1, const u16* B1, int K1, const u16* A2, const u16* B2, int K2,
                  const float* bias, float bscale, void* out, int Nout, int rows, int Mstore,
                  int mode) {
    dim3 b(256);
    if (mode == 0) {
      int NT = Nout / 128;
      dim3 g((rows / 128) * NT);
      k_gemm<128, 0><<<g, b, 0, stream>>>(A1, B1, K1, A2, B2, K2, bias, bscale, out, Nout, Mstore,
                                          NT, nullptr, nullptr, 0, 0);
    } else if (mode == 1) {
      int NT = Nout / 128;
      dim3 g((rows / 128) * NT);
      k_gemm<128, 1><<<g, b, 0, stream>>>(A1, B1, K1, A2, B2, K2, bias, bscale, out, Nout, Mstore,
                                          NT, nullptr, nullptr, 0, 0);
    } else {
      int NT = Nout / 64;
      dim3 g((rows / 128) * NT);
      k_gemm<64, 2><<<g, b, 0, stream>>>(A1, B1, K1, A2, B2, K2, bias, bscale, out, Nout, Mstore,
                                         NT, nullptr, nullptr, 0, 0);
    }
  };
  auto lstm_step = [&](const u16* xt, const u16* wih, const u16* hprev, const u16* whh,
                       const float* bias, u16* hout, float* hsumP, int rows, int first, int dosum) {
    dim3 g((rows / 128) * 8), b(256);
    k_gemm<128, 3><<<g, b, 0, stream>>>(xt, wih, 256, hprev, whh, 256, bias, 1.f,
                                        hout, 256, rows, 8, cst, hsumP, first, dosum);
  };

  // ---- conv1 via linearity: y1 = xb@W1 (no bias); z = relu(gather(y1)+b1); x1 = relu(z@W2+b2) ----
  gemm(xb, wt[0], 512, nullptr, nullptr, 0, nullptr, 0.f, y1, 256, Mpad, Mpad, 0);
  for (int base = 0; base < Mpad; base += McC) {
    int rows = Mpad - base < McC ? Mpad - base : McC;
    int ab = (rows + 3) / 4;
    k_aggbr<<<ab, 256, 0, stream>>>(y1, rowstart, esrc, (const float*)d_in[3], zC, N, base, rows);
    gemm(zC, wt[1], 256, nullptr, nullptr, 0, (const float*)d_in[5], 1.f,
         xl[0] + (size_t)base * 256, 256, rows, rows, 1);
  }
  // ---- conv2-4 (h-space gather) ----
  for (int l = 1; l < 4; ++l) {
    const int cb1[4] = {3, 7, 11, 15}, cb2[4] = {5, 9, 13, 17};
    for (int base = 0; base < Mpad; base += McC) {
      int rows = Mpad - base < McC ? Mpad - base : McC;
      int ab = (rows + 3) / 4;
      k_agg256<<<ab, 256, 0, stream>>>(xl[l - 1], rowstart, esrc, zC, N, base, rows);
      gemm((u16*)zC, wt[2 * l], 256, nullptr, nullptr, 0, (const float*)d_in[cb1[l]], 1.f,
           y1, 256, rows, rows, 1);
      gemm(y1, wt[2 * l + 1], 256, nullptr, nullptr, 0, (const float*)d_in[cb2[l]], 1.f,
           xl[l] + (size_t)base * 256, 256, rows, rows, 1);
    }
  }
  // ---- residual cascade in place ----
  k_cascade<<<(Mpad * 64 + 255) / 256, 256, 0, stream>>>(xl[0], xl[1], xl[2], xl[3], Mpad * 64);

  // ---- LSTM + final (gates fused, gate-sliced tiles, bf16 c) ----
  const float* b_l0 = (const float*)d_in[20];
  const float* b_l1 = (const float*)d_in[23];
  const float* b_mlp = (const float*)d_in[25];
  for (int base = 0; base < Mpad; base += McL) {
    int rows = Mpad - base < McL ? Mpad - base : McL;
    const size_t boff = (size_t)base * 256;
    for (int t = 0; t < 4; ++t)  // layer 0
      lstm_step(xl[t] + boff, wt[8], t ? h0s[t - 1] : nullptr, wt[9], b_l0,
                h0s[t], nullptr, rows, t == 0, 0);
    for (int t = 0; t < 4; ++t)  // layer 1 (accumulate hsum)
      lstm_step(h0s[t], wt[10], t ? h1p[(t + 1) & 1] : nullptr, wt[11], b_l1,
                h1p[t & 1], hsum, rows, t == 0, 1);
    k_sfin<<<(rows * 64 + 255) / 256, 256, 0, stream>>>(xl[0] + boff, xl[1] + boff, xl[2] + boff,
                                                        xl[3] + boff, hsum, sbc, rows * 64);
    int st = N - base;
    if (st > rows) st = rows;
    if (st > 0)
      gemm(sbc, wt[12], 256, nullptr, nullptr, 0, b_mlp, 3.f,
           (float*)d_out + boff, 256, rows, st, 2);
  }
}

// Round 19
// 1418.381 us; speedup vs baseline: 1.6475x; 1.0122x over previous
//
#include <hip/hip_runtime.h>

typedef unsigned int u32;
typedef unsigned short u16;

typedef __attribute__((ext_vector_type(8))) __bf16 bf16x8;
typedef __attribute__((ext_vector_type(4))) float f32x4;

__device__ __forceinline__ u16 f2bf(float f) {
  u32 u = __float_as_uint(f);
  u += 0x7fffu + ((u >> 16) & 1u);
  return (u16)(u >> 16);
}
__device__ __forceinline__ float bl(u32 u) { return __uint_as_float(u << 16); }
__device__ __forceinline__ float bh(u32 u) { return __uint_as_float(u & 0xffff0000u); }
__device__ __forceinline__ u32 pk2(float a, float b) { return (u32)f2bf(a) | ((u32)f2bf(b) << 16); }
__device__ __forceinline__ float fsig(float x) { return 1.f / (1.f + __expf(-x)); }
__device__ __forceinline__ float ftanh(float x) { return 1.f - 2.f / (__expf(2.f * x) + 1.f); }

#define GLDS16(gp, lp)                                                                  \
  __builtin_amdgcn_global_load_lds((const __attribute__((address_space(1))) u32*)(gp),  \
                                   (__attribute__((address_space(3))) u32*)(lp), 16, 0, 0)

// ---------- batched weight transpose+cast: wt[c*K+k] = bf16(w[k*N+c]) ----------
struct WTargs {
  const float* src[13];
  u16* dst[13];
  int K[13];
  int Nc[13];
  int bstart[14];
};
__global__ __launch_bounds__(256) void k_wtall(WTargs wa) {
  int b = blockIdx.x;
  int w = 0;
  while (b >= wa.bstart[w + 1]) ++w;
  int i = (b - wa.bstart[w]) * 256 + threadIdx.x;
  int K = wa.K[w], Nc = wa.Nc[w];
  if (i >= K * Nc) return;
  int k = i / Nc, c = i - k * Nc;
  wa.dst[w][(size_t)c * K + k] = f2bf(wa.src[w][i]);
}

// ---------- x fp32 [N,512] -> bf16 xb ----------
__global__ __launch_bounds__(256) void k_x2bf(const float* __restrict__ x, u16* __restrict__ xb, int total8) {
  int i = blockIdx.x * 256 + threadIdx.x;
  if (i >= total8) return;
  size_t o = (size_t)i * 8;
  float4 a = *(const float4*)(x + o), b = *(const float4*)(x + o + 4);
  uint4 v;
  v.x = pk2(a.x, a.y); v.y = pk2(a.z, a.w); v.z = pk2(b.x, b.y); v.w = pk2(b.z, b.w);
  *(uint4*)(xb + o) = v;
}

// ---------- CSR build ----------
__global__ void k_hist(const int* __restrict__ dst, int* __restrict__ deg, int E) {
  int e = blockIdx.x * 256 + threadIdx.x;
  if (e < E) atomicAdd(&deg[dst[e]], 1);
}
__global__ __launch_bounds__(1024) void k_scan1(const int* __restrict__ deg, int* __restrict__ rs,
                                                int* __restrict__ bsum, int n) {
  __shared__ int buf[1024];
  int t = threadIdx.x, idx = blockIdx.x * 1024 + t;
  int v = idx < n ? deg[idx] : 0;
  buf[t] = v;
  __syncthreads();
  for (int off = 1; off < 1024; off <<= 1) {
    int u = t >= off ? buf[t - off] : 0;
    __syncthreads();
    buf[t] += u;
    __syncthreads();
  }
  if (idx < n) rs[idx + 1] = buf[t];
  if (t == 1023) bsum[blockIdx.x] = buf[1023];
}
__global__ void k_scan2(int* bsum, int nb) {
  if (threadIdx.x == 0) {
    int s = 0;
    for (int b = 0; b < nb; ++b) { s += bsum[b]; bsum[b] = s; }
  }
}
__global__ void k_scan3(const int* __restrict__ bsum, int* __restrict__ rs,
                        int* __restrict__ cursor, int n) {
  int i = blockIdx.x * 256 + threadIdx.x;
  if (i >= n) return;
  int b = i >> 10;
  int add = b ? bsum[b - 1] : 0;
  int v = rs[i + 1] + add;  // inclusive prefix
  int d = cursor[i];        // deg
  rs[i + 1] = v;
  cursor[i] = v - d;        // exclusive prefix = scatter cursor
  if (i == 0) rs[0] = 0;
}
__global__ void k_scatter(const int* __restrict__ src, const int* __restrict__ dst,
                          int* __restrict__ cursor, int* __restrict__ esrc, int E) {
  int e = blockIdx.x * 256 + threadIdx.x;
  if (e < E) {
    int p = atomicAdd(&cursor[dst[e]], 1);
    esrc[p] = src[e];
  }
}

// ---------- conv1 projected-space gather: z = relu(y[node] + sum_nb y[src] + b1) ----------
__global__ __launch_bounds__(256) void k_aggbr(const u16* __restrict__ y, const int* __restrict__ rowstart,
                                               const int* __restrict__ esrc, const float* __restrict__ b1,
                                               u16* __restrict__ z, int Nn, int base, int rows) {
  int lane = threadIdx.x & 63, wid = threadIdx.x >> 6;
  int r = blockIdx.x * 4 + wid;
  if (r >= rows) return;
  int node = base + r;
  const int cb = lane * 4;
  u16* orow = z + (size_t)r * 256 + cb;
  if (node >= Nn) { *(uint2*)orow = uint2{0, 0}; return; }
  float acc[4];
  {
    uint2 v = *(const uint2*)(y + (size_t)node * 256 + cb);
    acc[0] = bl(v.x); acc[1] = bh(v.x); acc[2] = bl(v.y); acc[3] = bh(v.y);
  }
  int s = rowstart[node], e = rowstart[node + 1];
  int j = s;
  for (; j + 3 < e; j += 4) {
    uint2 v0 = *(const uint2*)(y + (size_t)esrc[j] * 256 + cb);
    uint2 v1 = *(const uint2*)(y + (size_t)esrc[j + 1] * 256 + cb);
    uint2 v2 = *(const uint2*)(y + (size_t)esrc[j + 2] * 256 + cb);
    uint2 v3 = *(const uint2*)(y + (size_t)esrc[j + 3] * 256 + cb);
    acc[0] += (bl(v0.x) + bl(v1.x)) + (bl(v2.x) + bl(v3.x));
    acc[1] += (bh(v0.x) + bh(v1.x)) + (bh(v2.x) + bh(v3.x));
    acc[2] += (bl(v0.y) + bl(v1.y)) + (bl(v2.y) + bl(v3.y));
    acc[3] += (bh(v0.y) + bh(v1.y)) + (bh(v2.y) + bh(v3.y));
  }
  for (; j < e; ++j) {
    uint2 v = *(const uint2*)(y + (size_t)esrc[j] * 256 + cb);
    acc[0] += bl(v.x); acc[1] += bh(v.x); acc[2] += bl(v.y); acc[3] += bh(v.y);
  }
  float4 bb = *(const float4*)(b1 + cb);
  acc[0] = fmaxf(acc[0] + bb.x, 0.f);
  acc[1] = fmaxf(acc[1] + bb.y, 0.f);
  acc[2] = fmaxf(acc[2] + bb.z, 0.f);
  acc[3] = fmaxf(acc[3] + bb.w, 0.f);
  uint2 o;
  o.x = pk2(acc[0], acc[1]); o.y = pk2(acc[2], acc[3]);
  *(uint2*)orow = o;
}

// ---------- conv2-4 aggregation from bf16 h [Mpad,256] ----------
__global__ __launch_bounds__(256) void k_agg256(const u16* __restrict__ h,
                                                const int* __restrict__ rowstart,
                                                const int* __restrict__ esrc,
                                                u16* __restrict__ out, int Nn, int base, int rows) {
  int lane = threadIdx.x & 63, wid = threadIdx.x >> 6;
  int r = blockIdx.x * 4 + wid;
  if (r >= rows) return;
  int node = base + r;
  const int cb = lane * 4;
  u16* orow = out + (size_t)r * 256 + cb;
  if (node >= Nn) { *(uint2*)orow = uint2{0, 0}; return; }
  float acc[4];
  {
    uint2 v = *(const uint2*)(h + (size_t)node * 256 + cb);
    acc[0] = bl(v.x); acc[1] = bh(v.x); acc[2] = bl(v.y); acc[3] = bh(v.y);
  }
  int s = rowstart[node], e = rowstart[node + 1];
  int j = s;
  for (; j + 3 < e; j += 4) {
    uint2 v0 = *(const uint2*)(h + (size_t)esrc[j] * 256 + cb);
    uint2 v1 = *(const uint2*)(h + (size_t)esrc[j + 1] * 256 + cb);
    uint2 v2 = *(const uint2*)(h + (size_t)esrc[j + 2] * 256 + cb);
    uint2 v3 = *(const uint2*)(h + (size_t)esrc[j + 3] * 256 + cb);
    acc[0] += (bl(v0.x) + bl(v1.x)) + (bl(v2.x) + bl(v3.x));
    acc[1] += (bh(v0.x) + bh(v1.x)) + (bh(v2.x) + bh(v3.x));
    acc[2] += (bl(v0.y) + bl(v1.y)) + (bl(v2.y) + bl(v3.y));
    acc[3] += (bh(v0.y) + bh(v1.y)) + (bh(v2.y) + bh(v3.y));
  }
  for (; j < e; ++j) {
    uint2 v = *(const uint2*)(h + (size_t)esrc[j] * 256 + cb);
    acc[0] += bl(v.x); acc[1] += bh(v.x); acc[2] += bl(v.y); acc[3] += bh(v.y);
  }
  uint2 o;
  o.x = pk2(acc[0], acc[1]); o.y = pk2(acc[2], acc[3]);
  *(uint2*)orow = o;
}

// ---------- bf16 MFMA GEMM (round-16-proven): glds staging + XOR-swizzled LDS + XCD swizzle ----------
// Single-buffered LDS, __syncthreads-paced. 128xBN tile, BK=64, 4 waves 2x2 — the occupancy/density
// sweet spot: deeper pipelines (r15) and bigger tiles (r17) both regressed via lost blocks/CU.
// MODE 0: bf16 out, 1: relu bf16 out, 2: relu fp32 out; MODE 3: fused LSTM gates
// (gate-sliced B tiles; c-state bf16; hsum bf16 — numerics proven in r17).
template <int BN, int MODE>
__global__ __launch_bounds__(256) void k_gemm(const u16* __restrict__ A1, const u16* __restrict__ B1, int K1,
                                              const u16* __restrict__ A2, const u16* __restrict__ B2, int K2,
                                              const float* __restrict__ bias, float bscale,
                                              void* __restrict__ outp, int Nout, int Mstore, int NT,
                                              u16* __restrict__ cstp, u16* __restrict__ hsump,
                                              int first, int dosum) {
  constexpr int NF = BN / 32;
  __shared__ u16 Al[128 * 64];
  __shared__ u16 Bl[BN * 64];
  const int tid = threadIdx.x;
  const int lane = tid & 63, wid = tid >> 6;
  const int wr = wid >> 1, wc = wid & 1;
  // bijective XCD swizzle (m204)
  const int nwg = gridDim.x;
  const int orig = blockIdx.x;
  const int q = nwg >> 3, rr8 = nwg & 7;
  const int xcd = orig & 7;
  const int wgid = (xcd < rr8 ? xcd * (q + 1) : rr8 * (q + 1) + (xcd - rr8) * q) + (orig >> 3);
  const int mtile = wgid / NT, ntile = wgid - mtile * NT;
  const int m0 = mtile * 128;
  const int n0 = ntile * BN;       // MODE<3 column base
  const int h0 = ntile * 32;       // MODE==3 hcol base
  const int l15 = lane & 15, l4 = lane >> 4;
  const int srow = lane >> 3;
  const int scol = ((lane & 7) ^ (lane >> 3)) * 8;  // pre-swizzled global column slot
  const int rsw = l15 & 7;                          // read-side row XOR key
  f32x4 acc[4][NF] = {};

  for (int s = 0; s < 2; ++s) {
    const u16* A = s ? A2 : A1;
    const u16* B = s ? B2 : B1;
    const int K = s ? K2 : K1;
    if (A == nullptr) continue;
    for (int k0 = 0; k0 < K; k0 += 64) {
      __syncthreads();  // previous tile's LDS reads done before overwrite
#pragma unroll
      for (int p = 0; p < 4; ++p) {
        int r = m0 + p * 32 + wid * 8 + srow;
        GLDS16(A + (size_t)r * K + k0 + scol, &Al[(p * 32 + wid * 8) * 64]);
      }
#pragma unroll
      for (int p = 0; p < NF; ++p) {
        int r;
        if constexpr (MODE == 3) r = p * 256 + h0 + wid * 8 + srow;  // gate p rows
        else r = n0 + p * 32 + wid * 8 + srow;
        GLDS16(B + (size_t)r * K + k0 + scol, &Bl[(p * 32 + wid * 8) * 64]);
      }
      __syncthreads();  // compiler drains vmcnt before barrier
#pragma unroll
      for (int ks = 0; ks < 2; ++ks) {
        const int sp = (((ks * 4 + l4) ^ rsw)) * 8;  // swizzled 16B-slot within row
        bf16x8 af[4], bfr[NF];
#pragma unroll
        for (int m = 0; m < 4; ++m)
          af[m] = *(const bf16x8*)&Al[(wr * 64 + m * 16 + l15) * 64 + sp];
#pragma unroll
        for (int n = 0; n < NF; ++n) {
          int trow;
          if constexpr (MODE == 3) trow = n * 32 + wc * 16 + l15;  // gate n, hcol subset
          else trow = wc * (BN / 2) + n * 16 + l15;
          bfr[n] = *(const bf16x8*)&Bl[trow * 64 + sp];
        }
#pragma unroll
        for (int m = 0; m < 4; ++m)
#pragma unroll
          for (int n = 0; n < NF; ++n)
            acc[m][n] = __builtin_amdgcn_mfma_f32_16x16x32_bf16(af[m], bfr[n], acc[m][n], 0, 0, 0);
      }
    }
  }

  if constexpr (MODE == 3) {
    const int hcol = h0 + wc * 16 + l15;
    const float bi = bias[hcol], bf2 = bias[256 + hcol];
    const float bg = bias[512 + hcol], bo = bias[768 + hcol];
    u16* hout = (u16*)outp;
#pragma unroll
    for (int m = 0; m < 4; ++m) {
      int gr0 = m0 + wr * 64 + m * 16 + l4 * 4;
#pragma unroll
      for (int r = 0; r < 4; ++r) {
        int gr = gr0 + r;
        if (gr >= Mstore) continue;
        float gi = acc[m][0][r] + bi;
        float gf = acc[m][1][r] + bf2;
        float gg = acc[m][2][r] + bg;
        float go = acc[m][3][r] + bo;
        size_t o = (size_t)gr * 256 + hcol;
        float nc = fsig(gi) * ftanh(gg);
        if (!first) nc += fsig(gf) * bl((u32)cstp[o]);
        cstp[o] = f2bf(nc);
        nc = bl((u32)f2bf(nc));  // use stored-precision c for h (consistency)
        float h = fsig(go) * ftanh(nc);
        hout[o] = f2bf(h);
        if (dosum) {
          if (first) hsump[o] = f2bf(h);
          else hsump[o] = f2bf(bl((u32)hsump[o]) + h);
        }
      }
    }
    return;
  }

#pragma unroll
  for (int m = 0; m < 4; ++m) {
    int gr0 = m0 + wr * 64 + m * 16 + l4 * 4;
#pragma unroll
    for (int n = 0; n < NF; ++n) {
      int gc = n0 + wc * (BN / 2) + n * 16 + l15;
      float bb = bias ? bias[gc] * bscale : 0.f;
#pragma unroll
      for (int r = 0; r < 4; ++r) {
        int gr = gr0 + r;
        if (gr >= Mstore) continue;
        float v = acc[m][n][r] + bb;
        if (MODE >= 1) v = fmaxf(v, 0.f);
        if (MODE == 2) ((float*)outp)[(size_t)gr * Nout + gc] = v;
        else ((u16*)outp)[(size_t)gr * Nout + gc] = f2bf(v);
      }
    }
  }
}

// ---------- residual cascade in place ----------
__global__ __launch_bounds__(256) void k_cascade(const u16* __restrict__ x1, u16* __restrict__ x2,
                                                 u16* __restrict__ x3, u16* __restrict__ x4, int total4) {
  int i = blockIdx.x * 256 + threadIdx.x;
  if (i >= total4) return;
  size_t o = (size_t)i * 4;
  uint2 v1 = *(const uint2*)(x1 + o), v2 = *(const uint2*)(x2 + o);
  uint2 v3 = *(const uint2*)(x3 + o), v4 = *(const uint2*)(x4 + o);
  float a1[4] = {bl(v1.x), bh(v1.x), bl(v1.y), bh(v1.y)};
  float a2[4] = {bl(v2.x), bh(v2.x), bl(v2.y), bh(v2.y)};
  float a3[4] = {bl(v3.x), bh(v3.x), bl(v3.y), bh(v3.y)};
  float a4[4] = {bl(v4.x), bh(v4.x), bl(v4.y), bh(v4.y)};
  float y2[4], y3[4], y4[4];
#pragma unroll
  for (int j = 0; j < 4; ++j) {
    y2[j] = a2[j] + a1[j];
    y3[j] = a3[j] + y2[j];
    y4[j] = a4[j] + y3[j];
  }
  *(uint2*)(x2 + o) = uint2{pk2(y2[0], y2[1]), pk2(y2[2], y2[3])};
  *(uint2*)(x3 + o) = uint2{pk2(y3[0], y3[1]), pk2(y3[2], y3[3])};
  *(uint2*)(x4 + o) = uint2{pk2(y4[0], y4[1]), pk2(y4[2], y4[3])};
}

// ---------- s = 1.4*(x1+x2+x3+x4) + 0.25*hsum  (hsum bf16) ----------
__global__ __launch_bounds__(256) void k_sfin(const u16* __restrict__ x1, const u16* __restrict__ x2,
                                              const u16* __restrict__ x3, const u16* __restrict__ x4,
                                              const u16* __restrict__ hsum, u16* __restrict__ sb,
                                              int total4) {
  int i = blockIdx.x * 256 + threadIdx.x;
  if (i >= total4) return;
  size_t o = (size_t)i * 4;
  uint2 v1 = *(const uint2*)(x1 + o), v2 = *(const uint2*)(x2 + o);
  uint2 v3 = *(const uint2*)(x3 + o), v4 = *(const uint2*)(x4 + o);
  uint2 vh = *(const uint2*)(hsum + o);
  float hh[4] = {bl(vh.x), bh(vh.x), bl(vh.y), bh(vh.y)};
  float r0 = 1.4f * (bl(v1.x) + bl(v2.x) + bl(v3.x) + bl(v4.x)) + 0.25f * hh[0];
  float r1 = 1.4f * (bh(v1.x) + bh(v2.x) + bh(v3.x) + bh(v4.x)) + 0.25f * hh[1];
  float r2 = 1.4f * (bl(v1.y) + bl(v2.y) + bl(v3.y) + bl(v4.y)) + 0.25f * hh[2];
  float r3 = 1.4f * (bh(v1.y) + bh(v2.y) + bh(v3.y) + bh(v4.y)) + 0.25f * hh[3];
  *(uint2*)(sb + o) = uint2{pk2(r0, r1), pk2(r2, r3)};
}

extern "C" void kernel_launch(void* const* d_in, const int* in_sizes, int n_in,
                              void* d_out, int out_size, void* d_ws, size_t ws_size,
                              hipStream_t stream) {
  (void)n_in; (void)out_size;
  const int N = in_sizes[0] / 512;          // 50000
  const int E = in_sizes[1] / 2;            // 800000
  const int Mpad = ((N + 127) / 128) * 128; // 50176
  auto al128 = [](int v) { return ((v + 127) / 128) * 128; };

  const float* x = (const float*)d_in[0];
  const int* ei = (const int*)d_in[1];
  const int* esrc_in = ei;
  const int* edst_in = ei + E;

  // ---- workspace arena ----
  size_t off = 0;
  auto alloc = [&](size_t bytes) { size_t o = off; off += (bytes + 255) & ~(size_t)255; return o; };
  char* ws = (char*)d_ws;
  const size_t szH = (size_t)Mpad * 256 * 2;   // 25.7 MB
  const size_t szXB = (size_t)Mpad * 512 * 2;  // 51.4 MB
  const int widx[13] = {2, 4, 6, 8, 10, 12, 14, 16, 18, 19, 21, 22, 24};
  const int wK[13] = {512, 256, 256, 256, 256, 256, 256, 256, 256, 256, 256, 256, 256};
  const int wN[13] = {256, 256, 256, 256, 256, 256, 256, 256, 1024, 1024, 1024, 1024, 256};
  size_t wt_o[13];
  for (int i = 0; i < 13; ++i) wt_o[i] = alloc((size_t)wK[i] * wN[i] * 2);
  size_t rowstart_o = alloc((size_t)(N + 1) * 4);
  size_t cursor_o = alloc((size_t)N * 4);
  size_t bsum_o = alloc(256 * 4);
  size_t esrc_o = alloc((size_t)E * 4);
  size_t x_o[4];
  for (int t = 0; t < 4; ++t) x_o[t] = alloc(szH);
  // tmp union region:
  //  conv phase:  [xb szXB][y1 szH][z McC*512]
  //  lstm phase:  [h0s x4][h1p x2][cst][sbc][hsum] all bf16 = McL*4608 B  (9 x 512B/row)
  int McC = al128((Mpad + 3) / 4);
  int McL = al128((Mpad + 7) / 8);
  {
    const int ccand[3] = {Mpad, al128((Mpad + 1) / 2), al128((Mpad + 3) / 4)};
    const int lcand[5] = {Mpad, al128((Mpad + 1) / 2), 16384, 8192, al128((Mpad + 7) / 8)};
    bool done = false;
    for (int ci = 0; ci < 3 && !done; ++ci) {
      for (int li = 0; li < 5 && !done; ++li) {
        size_t cneed = szXB + szH + (size_t)ccand[ci] * 512;
        size_t lneed = (size_t)lcand[li] * 4608;
        size_t tmp = cneed > lneed ? cneed : lneed;
        if (off + tmp + (1u << 20) <= ws_size) { McC = ccand[ci]; McL = lcand[li]; done = true; }
      }
    }
  }
  const size_t hb = (size_t)McL * 256 * 2;
  size_t lstm_sz = 9 * hb;
  size_t conv_sz = szXB + szH + (size_t)McC * 512;
  size_t tmp_o = alloc(lstm_sz > conv_sz ? lstm_sz : conv_sz);
  if (off > ws_size) return;

  u16* wt[13];
  for (int i = 0; i < 13; ++i) wt[i] = (u16*)(ws + wt_o[i]);
  int* rowstart = (int*)(ws + rowstart_o);
  int* cursor = (int*)(ws + cursor_o);
  int* bsum = (int*)(ws + bsum_o);
  int* esrc = (int*)(ws + esrc_o);
  u16* xl[4];
  for (int t = 0; t < 4; ++t) xl[t] = (u16*)(ws + x_o[t]);
  // conv views
  u16* xb = (u16*)(ws + tmp_o);
  u16* y1 = (u16*)(ws + tmp_o + szXB);
  u16* zC = (u16*)(ws + tmp_o + szXB + szH);
  // lstm views (overlay same region; conv temps dead by then)
  u16* h0s[4];
  for (int t = 0; t < 4; ++t) h0s[t] = (u16*)(ws + tmp_o + t * hb);
  u16* h1p[2] = {(u16*)(ws + tmp_o + 4 * hb), (u16*)(ws + tmp_o + 5 * hb)};
  u16* cst = (u16*)(ws + tmp_o + 6 * hb);
  u16* sbc = (u16*)(ws + tmp_o + 7 * hb);
  u16* hsum = (u16*)(ws + tmp_o + 8 * hb);

  // ---- weight prep + x->bf16 (pad rows zeroed) ----
  WTargs wa;
  int bacc = 0;
  for (int i = 0; i < 13; ++i) {
    wa.src[i] = (const float*)d_in[widx[i]];
    wa.dst[i] = wt[i];
    wa.K[i] = wK[i];
    wa.Nc[i] = wN[i];
    wa.bstart[i] = bacc;
    bacc += (wK[i] * wN[i] + 255) / 256;
  }
  wa.bstart[13] = bacc;
  k_wtall<<<bacc, 256, 0, stream>>>(wa);
  k_x2bf<<<(N * 64 + 255) / 256, 256, 0, stream>>>(x, xb, N * 64);
  if (Mpad > N) hipMemsetAsync(xb + (size_t)N * 512, 0, (size_t)(Mpad - N) * 512 * 2, stream);
  // ---- CSR (hierarchical scan) ----
  hipMemsetAsync(cursor, 0, (size_t)N * 4, stream);
  k_hist<<<(E + 255) / 256, 256, 0, stream>>>(edst_in, cursor, E);
  const int nb = (N + 1023) / 1024;
  k_scan1<<<nb, 1024, 0, stream>>>(cursor, rowstart, bsum, N);
  k_scan2<<<1, 64, 0, stream>>>(bsum, nb);
  k_scan3<<<(N + 255) / 256, 256, 0, stream>>>(bsum, rowstart, cursor, N);
  k_scatter<<<(E + 255) / 256, 256, 0, stream>>>(esrc_in, edst_in, cursor, esrc, E);

  // mode: 0 = bf16-out (BN=128), 1 = relu bf16-out (BN=128), 2 = relu fp32-out (BN=64)
  auto gemm = [&](const u16* A1, const u16* B1, int K1, const u16* A2, const u16* B2, int K2,
                  const float* bias, float bscale, void* out, int Nout, int rows, int Mstore,
                  int mode) {
    dim3 b(256);
    if (mode == 0) {
      int NT = Nout / 128;
      dim3 g((rows / 128) * NT);
      k_gemm<128, 0><<<g, b, 0, stream>>>(A1, B1, K1, A2, B2, K2, bias, bscale, out, Nout, Mstore,
                                          NT, nullptr, nullptr, 0, 0);
    } else if (mode == 1) {
      int NT = Nout / 128;
      dim3 g((rows / 128) * NT);
      k_gemm<128, 1><<<g, b, 0, stream>>>(A1, B1, K1, A2, B2, K2, bias, bscale, out, Nout, Mstore,
                                          NT, nullptr, nullptr, 0, 0);
    } else {
      int NT = Nout / 64;
      dim3 g((rows / 128) * NT);
      k_gemm<64, 2><<<g, b, 0, stream>>>(A1, B1, K1, A2, B2, K2, bias, bscale, out, Nout, Mstore,
                                         NT, nullptr, nullptr, 0, 0);
    }
  };
  auto lstm_step = [&](const u16* xt, const u16* wih, const u16* hprev, const u16* whh,
                       const float* bias, u16* hout, u16* hsumP, int rows, int first, int dosum) {
    dim3 g((rows / 128) * 8), b(256);
    k_gemm<128, 3><<<g, b, 0, stream>>>(xt, wih, 256, hprev, whh, 256, bias, 1.f,
                                        hout, 256, rows, 8, cst, hsumP, first, dosum);
  };

  // ---- conv1 via linearity: y1 = xb@W1 (no bias); z = relu(gather(y1)+b1); x1 = relu(z@W2+b2) ----
  gemm(xb, wt[0], 512, nullptr, nullptr, 0, nullptr, 0.f, y1, 256, Mpad, Mpad, 0);
  for (int base = 0; base < Mpad; base += McC) {
    int rows = Mpad - base < McC ? Mpad - base : McC;
    int ab = (rows + 3) / 4;
    k_aggbr<<<ab, 256, 0, stream>>>(y1, rowstart, esrc, (const float*)d_in[3], zC, N, base, rows);
    gemm(zC, wt[1], 256, nullptr, nullptr, 0, (const float*)d_in[5], 1.f,
         xl[0] + (size_t)base * 256, 256, rows, rows, 1);
  }
  // ---- conv2-4 (h-space gather) ----
  for (int l = 1; l < 4; ++l) {
    const int cb1[4] = {3, 7, 11, 15}, cb2[4] = {5, 9, 13, 17};
    for (int base = 0; base < Mpad; base += McC) {
      int rows = Mpad - base < McC ? Mpad - base : McC;
      int ab = (rows + 3) / 4;
      k_agg256<<<ab, 256, 0, stream>>>(xl[l - 1], rowstart, esrc, zC, N, base, rows);
      gemm((u16*)zC, wt[2 * l], 256, nullptr, nullptr, 0, (const float*)d_in[cb1[l]], 1.f,
           y1, 256, rows, rows, 1);
      gemm(y1, wt[2 * l + 1], 256, nullptr, nullptr, 0, (const float*)d_in[cb2[l]], 1.f,
           xl[l] + (size_t)base * 256, 256, rows, rows, 1);
    }
  }
  // ---- residual cascade in place ----
  k_cascade<<<(Mpad * 64 + 255) / 256, 256, 0, stream>>>(xl[0], xl[1], xl[2], xl[3], Mpad * 64);

  // ---- LSTM + final (gates fused, gate-sliced tiles, bf16 c/hsum) ----
  const float* b_l0 = (const float*)d_in[20];
  const float* b_l1 = (const float*)d_in[23];
  const float* b_mlp = (const float*)d_in[25];
  for (int base = 0; base < Mpad; base += McL) {
    int rows = Mpad - base < McL ? Mpad - base : McL;
    const size_t boff = (size_t)base * 256;
    for (int t = 0; t < 4; ++t)  // layer 0
      lstm_step(xl[t] + boff, wt[8], t ? h0s[t - 1] : nullptr, wt[9], b_l0,
                h0s[t], nullptr, rows, t == 0, 0);
    for (int t = 0; t < 4; ++t)  // layer 1 (accumulate hsum)
      lstm_step(h0s[t], wt[10], t ? h1p[(t + 1) & 1] : nullptr, wt[11], b_l1,
                h1p[t & 1], hsum, rows, t == 0, 1);
    k_sfin<<<(rows * 64 + 255) / 256, 256, 0, stream>>>(xl[0] + boff, xl[1] + boff, xl[2] + boff,
                                                        xl[3] + boff, hsum, sbc, rows * 64);
    int st = N - base;
    if (st > rows) st = rows;
    if (st > 0)
      gemm(sbc, wt[12], 256, nullptr, nullptr, 0, b_mlp, 3.f,
           (float*)d_out + boff, 256, rows, st, 2);
  }
}